// Round 2
// baseline (123.348 us; speedup 1.0000x reference)
//
#include <hip/hip_runtime.h>
#include <hip/hip_bf16.h>
#include <math.h>

// Problem constants
#define N_TOK 16384
#define I_DIM 128
#define O_DIM 128
#define G_DIM 16
// GEMM tiling
#define BN 64                    // n-rows per block
#define KC 128                   // k per chunk (4 i-values x 16 g x {cos,sin})
#define NCHUNK 32                // chunk c covers i in {c, c+32, c+64, c+96}
#define A_STRIDE 136             // bf16 elems per LDS A row (272 B, padded)
#define C_STRIDE 132             // floats per LDS C row (epilogue)

typedef __bf16 bf16x8 __attribute__((ext_vector_type(8)));
typedef float  f32x4  __attribute__((ext_vector_type(4)));

// ---------------------------------------------------------------------------
// Pack cos/sin amplitudes (O,I,G) fp32 -> bf16 Bpack[c][o][kk]
//   kk = il*32 + g*2 + s  (s: 0=cos 1=sin),  i = il*32 + c  (il = 0..3)
// Fully coalesced float4 reads; 16 B interleaved writes.
// Thread u -> (o = u>>9, i = (u>>2)&127, gq = u&3)  handles g = 4*gq..4*gq+3.
// ---------------------------------------------------------------------------
__global__ __launch_bounds__(256) void fkan_pack_b(
    const float* __restrict__ cosA, const float* __restrict__ sinA,
    __hip_bfloat16* __restrict__ Bp)
{
    int u  = blockIdx.x * 256 + threadIdx.x;       // 0 .. 65535
    int gq = u & 3;
    int i  = (u >> 2) & 127;
    int o  = u >> 9;
    int base = (o * I_DIM + i) * G_DIM + gq * 4;
    float4 cv = *(const float4*)(cosA + base);
    float4 sv = *(const float4*)(sinA + base);
    union { __bf16 h[8]; uint4 v; } w;
    w.h[0] = (__bf16)cv.x; w.h[1] = (__bf16)sv.x;
    w.h[2] = (__bf16)cv.y; w.h[3] = (__bf16)sv.y;
    w.h[4] = (__bf16)cv.z; w.h[5] = (__bf16)sv.z;
    w.h[6] = (__bf16)cv.w; w.h[7] = (__bf16)sv.w;
    int c  = i & 31;
    int il = i >> 5;
    int kk0 = il * 32 + gq * 8;
    *(uint4*)((__bf16*)Bp + (size_t)c * (O_DIM * KC) + o * KC + kk0) = w.v;
}

// ---------------------------------------------------------------------------
// Fused: features -> bf16 MFMA GEMM (B frags direct from L2) -> bias -> LN
// Grid: 256 blocks x 256 threads. Block tile 64n x 128o. K = 4096.
// A double-buffered in LDS; one barrier per chunk; x preloaded in registers.
// Wave tile: 64n x 32o (4 m-tiles x 2 o-tiles of 16x16x32 MFMA).
// ---------------------------------------------------------------------------
__global__ __launch_bounds__(256) void fkan_main(
    const float* __restrict__ x,
    const __hip_bfloat16* __restrict__ Bp,
    const float* __restrict__ bias,
    const float* __restrict__ gamma,
    const float* __restrict__ beta,
    float* __restrict__ out)
{
    // LDS: 2 x (64 x 136 bf16) = 34816 B; epilogue C tile (64x132 f32 = 33792 B)
    // overlays the same region (no A reads after the K loop).
    __shared__ __align__(16) char smem[2 * 64 * A_STRIDE * 2];
    __bf16* As = (__bf16*)smem;
    float*  Cs = (float*)smem;

    const int t     = threadIdx.x;
    const int lane  = t & 63;
    const int wave  = t >> 6;
    const int row16 = lane & 15;
    const int quad  = lane >> 4;
    const int n0    = blockIdx.x * BN;

    // feature-staging assignment: thread t -> (fn = t/4, il = t%4), i = il*32 + c
    const int fn  = t >> 2;
    const int fil = t & 3;

    // ---- preload x: this thread's 32 values, contiguous in c ----
    float4 xr[8];
    {
        const float* xrow = x + (size_t)(n0 + fn) * I_DIM + fil * 32;
#pragma unroll
        for (int j = 0; j < 8; ++j) xr[j] = *(const float4*)(xrow + 4 * j);
    }

    f32x4 acc[4][2];
#pragma unroll
    for (int mt = 0; mt < 4; ++mt)
#pragma unroll
        for (int ot = 0; ot < 2; ++ot)
            acc[mt][ot] = (f32x4){0.f, 0.f, 0.f, 0.f};

    // ---- feature computation for one chunk into LDS buffer ----
    auto stage_feats = [&](int c, int buf) {
        const float* xf = (const float*)xr;
        float xv = xf[c];
        float s1, c1;
        __sincosf(xv, &s1, &c1);
        __align__(16) __bf16 feat[32];
        feat[0] = (__bf16)c1;
        feat[1] = (__bf16)s1;
        float ck = c1, sk = s1;
#pragma unroll
        for (int g = 1; g < 16; ++g) {
            float cn = ck * c1 - sk * s1;
            float sn = sk * c1 + ck * s1;
            feat[2 * g]     = (__bf16)cn;
            feat[2 * g + 1] = (__bf16)sn;
            ck = cn; sk = sn;
        }
        bf16x8* dst = (bf16x8*)(As + (size_t)buf * (64 * A_STRIDE) + fn * A_STRIDE + fil * 32);
        const bf16x8* srcv = (const bf16x8*)feat;
#pragma unroll
        for (int j = 0; j < 4; ++j) dst[j] = srcv[j];
    };

    // prologue: stage chunk 0
    stage_feats(0, 0);
    __syncthreads();

    const __hip_bfloat16* Bw = Bp + (size_t)wave * 32 * KC;   // this wave's o-rows

    for (int c = 0; c < NCHUNK; ++c) {
        const int buf = c & 1;

        // ---- B fragments for chunk c: direct global (L2) -> VGPR ----
        bf16x8 bfrag[4][2];
        {
            const __bf16* Bq = (const __bf16*)(Bw + (size_t)c * (O_DIM * KC));
#pragma unroll
            for (int ks = 0; ks < 4; ++ks)
#pragma unroll
                for (int ot = 0; ot < 2; ++ot)
                    bfrag[ks][ot] = *(const bf16x8*)(Bq + (ot * 16 + row16) * KC + ks * 32 + quad * 8);
        }

        // ---- stage features for chunk c+1 into the other buffer ----
        if (c + 1 < NCHUNK) stage_feats(c + 1, buf ^ 1);

        // ---- MFMA: 4 ksteps x (4 m-tiles x 2 o-tiles) ----
        const __bf16* Ab = As + (size_t)buf * (64 * A_STRIDE);
#pragma unroll
        for (int ks = 0; ks < 4; ++ks) {
            bf16x8 a[4];
#pragma unroll
            for (int mt = 0; mt < 4; ++mt)
                a[mt] = *(const bf16x8*)(Ab + (mt * 16 + row16) * A_STRIDE + ks * 32 + quad * 8);
#pragma unroll
            for (int mt = 0; mt < 4; ++mt)
#pragma unroll
                for (int ot = 0; ot < 2; ++ot)
                    acc[mt][ot] = __builtin_amdgcn_mfma_f32_16x16x32_bf16(
                        a[mt], bfrag[ks][ot], acc[mt][ot], 0, 0, 0);
        }
        __syncthreads();
    }

    // ---- epilogue: C -> LDS, bias + LayerNorm over O=128, store fp32 ----
    // C/D layout: col(o within 16) = lane&15, row(m within 16) = quad*4 + reg
#pragma unroll
    for (int mt = 0; mt < 4; ++mt)
#pragma unroll
        for (int ot = 0; ot < 2; ++ot)
#pragma unroll
            for (int r = 0; r < 4; ++r)
                Cs[(mt * 16 + quad * 4 + r) * C_STRIDE + wave * 32 + ot * 16 + row16] =
                    acc[mt][ot][r];
    __syncthreads();

    {
        const int r  = t >> 2;   // row within block (0..63)
        const int qt = t & 3;    // quarter of the O dim
        const float* crow = Cs + r * C_STRIDE + qt * 32;
        float vals[32];
        float sum = 0.f, sumsq = 0.f;
#pragma unroll
        for (int j = 0; j < 32; ++j) {
            float v = crow[j] + bias[qt * 32 + j];
            vals[j] = v;
            sum += v;
            sumsq += v * v;
        }
        sum   += __shfl_xor(sum, 1);   sum   += __shfl_xor(sum, 2);
        sumsq += __shfl_xor(sumsq, 1); sumsq += __shfl_xor(sumsq, 2);
        float mu  = sum * (1.0f / O_DIM);
        float var = sumsq * (1.0f / O_DIM) - mu * mu;
        float rstd = rsqrtf(var + 1e-5f);

        float* orow = out + (size_t)(n0 + r) * O_DIM + qt * 32;
#pragma unroll
        for (int jj = 0; jj < 8; ++jj) {
            float4 o4;
            o4.x = (vals[4 * jj + 0] - mu) * rstd * gamma[qt * 32 + 4 * jj + 0] + beta[qt * 32 + 4 * jj + 0];
            o4.y = (vals[4 * jj + 1] - mu) * rstd * gamma[qt * 32 + 4 * jj + 1] + beta[qt * 32 + 4 * jj + 1];
            o4.z = (vals[4 * jj + 2] - mu) * rstd * gamma[qt * 32 + 4 * jj + 2] + beta[qt * 32 + 4 * jj + 2];
            o4.w = (vals[4 * jj + 3] - mu) * rstd * gamma[qt * 32 + 4 * jj + 3] + beta[qt * 32 + 4 * jj + 3];
            *(float4*)(orow + 4 * jj) = o4;
        }
    }
}

extern "C" void kernel_launch(void* const* d_in, const int* in_sizes, int n_in,
                              void* d_out, int out_size, void* d_ws, size_t ws_size,
                              hipStream_t stream) {
    const float* x     = (const float*)d_in[0];
    const float* cosA  = (const float*)d_in[1];
    const float* sinA  = (const float*)d_in[2];
    const float* bias  = (const float*)d_in[3];
    const float* gamma = (const float*)d_in[4];
    const float* beta  = (const float*)d_in[5];
    float* out = (float*)d_out;

    __hip_bfloat16* Bp = (__hip_bfloat16*)d_ws;   // 1 MB: 32 chunks x 128 o x 128 k

    fkan_pack_b<<<dim3((O_DIM * I_DIM * 4) / 256), dim3(256), 0, stream>>>(cosA, sinA, Bp);
    fkan_main<<<dim3(N_TOK / BN), dim3(256), 0, stream>>>(x, Bp, bias, gamma, beta, out);
}